// Round 1
// baseline (2495.944 us; speedup 1.0000x reference)
//
#include <hip/hip_runtime.h>

namespace {
constexpr int H = 200, W = 200, HW = H * W;
constexpr int B = 4;
constexpr int NK = 81;
constexpr int TS = 16, HALO = 4, TLD = TS + 2 * HALO, TROW = TLD + 1; // 24, 25
constexpr int NTILE = 13; // ceil(200/16)
}

// ---------------- conv1x1 + bias + relu ----------------
// Input batch 0..3 from srcA, 4..7 from srcB (both (4,CIN,H,W)).
template <int CIN, int COUT>
__global__ __launch_bounds__(256) void conv1x1_relu_k(
    const float* __restrict__ srcA, const float* __restrict__ srcB,
    const float* __restrict__ w, const float* __restrict__ bias,
    float* __restrict__ out) {
  __shared__ float wt[CIN * COUT]; // transposed [ci][co]
  for (int i = threadIdx.x; i < CIN * COUT; i += 256) {
    int ci = i / COUT, co = i % COUT;
    wt[i] = w[co * CIN + ci];
  }
  __syncthreads();
  int p = blockIdx.x * 256 + threadIdx.x;
  int bb = p / HW, pix = p % HW;
  const float* src =
      (bb < B ? srcA + (size_t)bb * CIN * HW : srcB + (size_t)(bb - B) * CIN * HW) + pix;
  float acc[COUT];
#pragma unroll
  for (int co = 0; co < COUT; co++) acc[co] = bias[co];
  for (int ci = 0; ci < CIN; ci++) {
    float x = src[(size_t)ci * HW];
    const float4* w4 = (const float4*)&wt[ci * COUT];
#pragma unroll
    for (int q = 0; q < COUT / 4; q++) {
      float4 wv = w4[q];
      acc[4 * q + 0] += x * wv.x;
      acc[4 * q + 1] += x * wv.y;
      acc[4 * q + 2] += x * wv.z;
      acc[4 * q + 3] += x * wv.w;
    }
  }
  float* o = out + (size_t)bb * COUT * HW + pix;
#pragma unroll
  for (int co = 0; co < COUT; co++) o[(size_t)co * HW] = fmaxf(acc[co], 0.f);
}

// ---------------- conv3x3 (pad 1) + bias + relu ----------------
template <int CIN, int COUT>
__global__ __launch_bounds__(256) void conv3x3_relu_k(
    const float* __restrict__ src, const float* __restrict__ w,
    const float* __restrict__ bias, float* __restrict__ out) {
  __shared__ float wt[CIN * COUT]; // per-tap transposed [ci][co]
  int p = blockIdx.x * 256 + threadIdx.x;
  int bb = p / HW, pix = p % HW;
  int y = pix / W, x = pix % W;
  const float* s = src + (size_t)bb * CIN * HW;
  float acc[COUT];
#pragma unroll
  for (int co = 0; co < COUT; co++) acc[co] = 0.f;
  for (int tap = 0; tap < 9; tap++) {
    __syncthreads();
    for (int i = threadIdx.x; i < CIN * COUT; i += 256) {
      int ci = i / COUT, co = i % COUT;
      wt[i] = w[(co * CIN + ci) * 9 + tap];
    }
    __syncthreads();
    int yy = y + tap / 3 - 1, xx = x + tap % 3 - 1;
    if (yy >= 0 && yy < H && xx >= 0 && xx < W) {
      const float* sp = s + yy * W + xx;
      for (int ci = 0; ci < CIN; ci++) {
        float v = sp[(size_t)ci * HW];
        const float4* w4 = (const float4*)&wt[ci * COUT];
#pragma unroll
        for (int q = 0; q < COUT / 4; q++) {
          float4 wv = w4[q];
          acc[4 * q + 0] += v * wv.x;
          acc[4 * q + 1] += v * wv.y;
          acc[4 * q + 2] += v * wv.z;
          acc[4 * q + 3] += v * wv.w;
        }
      }
    }
  }
  float* o = out + (size_t)bb * COUT * HW + pix;
#pragma unroll
  for (int co = 0; co < COUT; co++)
    o[(size_t)co * HW] = fmaxf(acc[co] + bias[co], 0.f);
}

// ---------------- 81-offset correlation + fused softmax ----------------
// e: (8,64,H,W); batches 0..3 = select branch, 4..7 = current branch.
// wgt out: (4,81,H,W) normalized softmax weights.
__global__ __launch_bounds__(256) void corr_softmax_k(
    const float* __restrict__ e, float* __restrict__ wgt) {
  __shared__ float tile[16 * TLD * TROW]; // 38400 B, channel-plane layout
  int tileId = blockIdx.x;
  int tx0 = (tileId % NTILE) * TS, ty0 = (tileId / NTILE) * TS;
  int bb = blockIdx.y;
  int lx = threadIdx.x % TS, ly = threadIdx.x / TS;
  int x = tx0 + lx, y = ty0 + ly;
  bool active = (x < W && y < H);
  const float* es_base = e + (size_t)bb * 64 * HW + (active ? y * W + x : 0);
  const float* ec_base = e + (size_t)(bb + B) * 64 * HW;
  float acc[NK];
#pragma unroll
  for (int k = 0; k < NK; k++) acc[k] = 0.f;
  for (int cc = 0; cc < 4; cc++) { // 4 chunks of 16 channels
    __syncthreads();
    for (int i = threadIdx.x; i < TLD * TLD; i += 256) {
      int row = i / TLD, col = i % TLD;
      int gy = ty0 + row - HALO, gx = tx0 + col - HALO;
      bool v = (gy >= 0 && gy < H && gx >= 0 && gx < W);
      const float* p = ec_base + (size_t)(cc * 16) * HW + (v ? gy * W + gx : 0);
#pragma unroll
      for (int c = 0; c < 16; c++)
        tile[c * (TLD * TROW) + row * TROW + col] = v ? p[(size_t)c * HW] : 0.f;
    }
    __syncthreads();
    if (active) {
#pragma unroll
      for (int c = 0; c < 16; c++) {
        float es = es_base[(size_t)(cc * 16 + c) * HW];
        const float* tp = &tile[c * (TLD * TROW) + (ly + HALO) * TROW + (lx + HALO)];
#pragma unroll
        for (int k = 0; k < NK; k++) {
          int di = k / 9 - 4, dj = k % 9 - 4;
          acc[k] += es * tp[di * TROW + dj];
        }
      }
    }
  }
  if (!active) return;
  float m = acc[0];
#pragma unroll
  for (int k = 1; k < NK; k++) m = fmaxf(m, acc[k]);
  float ssum = 0.f;
#pragma unroll
  for (int k = 0; k < NK; k++) {
    acc[k] = expf(acc[k] - m);
    ssum += acc[k];
  }
  float inv = 1.f / ssum;
  int pix = y * W + x;
  float* wp = wgt + (size_t)bb * NK * HW + pix;
#pragma unroll
  for (int k = 0; k < NK; k++) wp[(size_t)k * HW] = acc[k] * inv;
}

// ---------------- weighted neighborhood aggregation (align) ----------------
// align[b,c,y,x] = sum_k wgt[b,k,y,x] * fs[b,c,y+di,x+dj]  (zero-padded)
__global__ __launch_bounds__(256) void align_k(
    const float* __restrict__ wgt, const float* __restrict__ fs,
    float* __restrict__ out) {
  __shared__ float tile[16 * TLD * TROW];
  int tileId = blockIdx.x;
  int tx0 = (tileId % NTILE) * TS, ty0 = (tileId / NTILE) * TS;
  int bb = blockIdx.y;
  int lx = threadIdx.x % TS, ly = threadIdx.x / TS;
  int x = tx0 + lx, y = ty0 + ly;
  bool active = (x < W && y < H);
  int pix = active ? y * W + x : 0;
  const float* fsb = fs + (size_t)bb * 128 * HW;
  float wreg[NK];
  const float* wp = wgt + (size_t)bb * NK * HW + pix;
#pragma unroll
  for (int k = 0; k < NK; k++) wreg[k] = wp[(size_t)k * HW];
  float* ob = out + (size_t)bb * 128 * HW + pix;
  for (int cc = 0; cc < 8; cc++) { // 8 chunks of 16 channels
    __syncthreads();
    for (int i = threadIdx.x; i < TLD * TLD; i += 256) {
      int row = i / TLD, col = i % TLD;
      int gy = ty0 + row - HALO, gx = tx0 + col - HALO;
      bool v = (gy >= 0 && gy < H && gx >= 0 && gx < W);
      const float* p = fsb + (size_t)(cc * 16) * HW + (v ? gy * W + gx : 0);
#pragma unroll
      for (int c = 0; c < 16; c++)
        tile[c * (TLD * TROW) + row * TROW + col] = v ? p[(size_t)c * HW] : 0.f;
    }
    __syncthreads();
    if (active) {
      float acc[16];
#pragma unroll
      for (int c = 0; c < 16; c++) acc[c] = 0.f;
#pragma unroll
      for (int c = 0; c < 16; c++) {
        const float* tp = &tile[c * (TLD * TROW) + (ly + HALO) * TROW + (lx + HALO)];
#pragma unroll
        for (int k = 0; k < NK; k++) {
          int di = k / 9 - 4, dj = k % 9 - 4;
          acc[c] += wreg[k] * tp[di * TROW + dj];
        }
      }
#pragma unroll
      for (int c = 0; c < 16; c++) ob[(size_t)(cc * 16 + c) * HW] = acc[c];
    }
  }
}

// ---------------- ag3 conv1x1 (32->1) + relu + 2-way softmax + blend ----------------
__global__ __launch_bounds__(256) void final_k(
    const float* __restrict__ a2, const float* __restrict__ w3,
    const float* __restrict__ b3, const float* __restrict__ alignb,
    const float* __restrict__ fcur, float* __restrict__ out) {
  int p = blockIdx.x * 256 + threadIdx.x;
  int bb = p / HW, pix = p % HW;
  const float* aS = a2 + (size_t)bb * 32 * HW + pix;
  const float* aC = a2 + (size_t)(bb + B) * 32 * HW + pix;
  float s0 = b3[0], s1 = b3[0];
#pragma unroll
  for (int c = 0; c < 32; c++) {
    float wv = w3[c];
    s0 += wv * aS[(size_t)c * HW];
    s1 += wv * aC[(size_t)c * HW];
  }
  s0 = fmaxf(s0, 0.f);
  s1 = fmaxf(s1, 0.f);
  float m = fmaxf(s0, s1);
  float e0 = expf(s0 - m), e1 = expf(s1 - m);
  float inv = 1.f / (e0 + e1);
  float p0 = e0 * inv, p1 = e1 * inv;
  const float* al = alignb + (size_t)bb * 128 * HW + pix;
  const float* fc = fcur + (size_t)bb * 128 * HW + pix;
  float* o = out + (size_t)bb * 128 * HW + pix;
#pragma unroll 4
  for (int c = 0; c < 128; c++)
    o[(size_t)c * HW] = p0 * al[(size_t)c * HW] + p1 * fc[(size_t)c * HW];
}

extern "C" void kernel_launch(void* const* d_in, const int* in_sizes, int n_in,
                              void* d_out, int out_size, void* d_ws, size_t ws_size,
                              hipStream_t stream) {
  const float* fsel = (const float*)d_in[0];
  const float* fcur = (const float*)d_in[1];
  const float* ec1_w = (const float*)d_in[2];
  const float* ec1_b = (const float*)d_in[3];
  const float* ec2_w = (const float*)d_in[4];
  const float* ec2_b = (const float*)d_in[5];
  const float* ag1_w = (const float*)d_in[6];
  const float* ag1_b = (const float*)d_in[7];
  const float* ag2_w = (const float*)d_in[8];
  const float* ag2_b = (const float*)d_in[9];
  const float* ag3_w = (const float*)d_in[10];
  const float* ag3_b = (const float*)d_in[11];

  const size_t S64 = (size_t)8 * 64 * HW; // floats per (8,64,H,W) buffer
  char* ws = (char*)d_ws;
  float* r0 = (float*)ws;                              // e1 -> wgt -> a2
  float* r1 = (float*)(ws + S64 * sizeof(float));      // e  -> a1
  float* r2 = (float*)(ws + 2 * S64 * sizeof(float));  // align
  float* e1 = r0;
  float* e = r1;
  float* wgt = r0;
  float* alignb = r2;
  float* a1 = r1;
  float* a2 = r0;
  float* outp = (float*)d_out;

  dim3 blk(256);
  // e1 = relu(conv1x1(cat, ec1))          (8,64,H,W)
  conv1x1_relu_k<128, 64><<<1250, blk, 0, stream>>>(fsel, fcur, ec1_w, ec1_b, e1);
  // e = relu(conv3x3(e1, ec2))            (8,64,H,W)
  conv3x3_relu_k<64, 64><<<1250, blk, 0, stream>>>(e1, ec2_w, ec2_b, e);
  // wgt = softmax(corr(e_sel, e_cur))     (4,81,H,W)
  corr_softmax_k<<<dim3(NTILE * NTILE, B), blk, 0, stream>>>(e, wgt);
  // align = sum_k wgt_k * shift(fsel)     (4,128,H,W)
  align_k<<<dim3(NTILE * NTILE, B), blk, 0, stream>>>(wgt, fsel, alignb);
  // a1 = relu(conv1x1(cat(align,fcur), ag1))  (8,64,H,W)
  conv1x1_relu_k<128, 64><<<1250, blk, 0, stream>>>(alignb, fcur, ag1_w, ag1_b, a1);
  // a2 = relu(conv3x3(a1, ag2))           (8,32,H,W)
  conv3x3_relu_k<64, 32><<<1250, blk, 0, stream>>>(a1, ag2_w, ag2_b, a2);
  // out = softmax2(ag3(a2)) blend         (4,128,H,W)
  final_k<<<625, blk, 0, stream>>>(a2, ag3_w, ag3_b, alignb, fcur, outp);
}

// Round 2
// 1641.693 us; speedup vs baseline: 1.5203x; 1.5203x over previous
//
#include <hip/hip_runtime.h>

namespace {
constexpr int H = 200, W = 200, HW = H * W;
constexpr int B = 4;
constexpr int NK = 81;
constexpr int TS = 16, HALO = 4, TLD = TS + 2 * HALO, TROW = TLD + 1; // 24, 25
constexpr int NTILE = 13; // ceil(200/16)
constexpr int PW = 208, PH = 202, PPLANE = PW * PH; // padded bf16 NHWC plane
}

typedef __attribute__((ext_vector_type(8))) short bf16x8;
typedef __attribute__((ext_vector_type(4))) float f32x4;

__device__ inline ushort f2bf(float f) {
  unsigned u = __float_as_uint(f);
  u += 0x7fffu + ((u >> 16) & 1u);
  return (ushort)(u >> 16);
}

// ---------------- zero fill (uint4 granularity) ----------------
__global__ __launch_bounds__(256) void zero_k(uint4* __restrict__ p, int n) {
  int i = blockIdx.x * 256 + threadIdx.x;
  if (i < n) p[i] = uint4{0u, 0u, 0u, 0u};
}

// ---------------- weight transform: OIHW fp32 -> [tap][co][ci] bf16 ----------------
__global__ __launch_bounds__(256) void wxform_k(const float* __restrict__ w,
                                                ushort* __restrict__ wb, int cout) {
  int i = blockIdx.x * 256 + threadIdx.x;
  int tot = cout * 64 * 9;
  if (i >= tot) return;
  int co = i / (64 * 9);
  int r = i % (64 * 9);
  int ci = r / 9, tap = r % 9;
  wb[(tap * cout + co) * 64 + ci] = f2bf(w[i]);
}

// ---------------- conv1x1 + bias + relu -> bf16 NHWC padded ----------------
// batches 0..3 from srcA, 4..7 from srcB (both (4,CIN,H,W) fp32 NCHW).
// out: [8][PPLANE][64] bf16, interior written at (y+1, x+1); borders pre-zeroed.
template <int CIN>
__global__ __launch_bounds__(256) void conv1x1_nhwc_k(
    const float* __restrict__ srcA, const float* __restrict__ srcB,
    const float* __restrict__ w, const float* __restrict__ bias,
    ushort* __restrict__ out) {
  __shared__ float wt[CIN * 64]; // transposed [ci][co]
  for (int i = threadIdx.x; i < CIN * 64; i += 256) {
    int ci = i >> 6, co = i & 63;
    wt[i] = w[co * CIN + ci];
  }
  __syncthreads();
  int p = blockIdx.x * 256 + threadIdx.x;
  int bb = p / HW, pix = p % HW;
  const float* src =
      (bb < B ? srcA + (size_t)bb * CIN * HW : srcB + (size_t)(bb - B) * CIN * HW) + pix;
  float acc[64];
#pragma unroll
  for (int co = 0; co < 64; co++) acc[co] = bias[co];
  for (int ci = 0; ci < CIN; ci++) {
    float x = src[(size_t)ci * HW];
    const float4* w4 = (const float4*)&wt[ci * 64];
#pragma unroll
    for (int q = 0; q < 16; q++) {
      float4 wv = w4[q];
      acc[4 * q + 0] += x * wv.x;
      acc[4 * q + 1] += x * wv.y;
      acc[4 * q + 2] += x * wv.z;
      acc[4 * q + 3] += x * wv.w;
    }
  }
  int y = pix / W, x = pix % W;
  ushort* o = out + ((size_t)bb * PPLANE + (size_t)(y + 1) * PW + (x + 1)) * 64;
  uint4* o4 = (uint4*)o;
#pragma unroll
  for (int g = 0; g < 8; g++) {
    unsigned u0 = (unsigned)f2bf(fmaxf(acc[8 * g + 0], 0.f)) |
                  ((unsigned)f2bf(fmaxf(acc[8 * g + 1], 0.f)) << 16);
    unsigned u1 = (unsigned)f2bf(fmaxf(acc[8 * g + 2], 0.f)) |
                  ((unsigned)f2bf(fmaxf(acc[8 * g + 3], 0.f)) << 16);
    unsigned u2 = (unsigned)f2bf(fmaxf(acc[8 * g + 4], 0.f)) |
                  ((unsigned)f2bf(fmaxf(acc[8 * g + 5], 0.f)) << 16);
    unsigned u3 = (unsigned)f2bf(fmaxf(acc[8 * g + 6], 0.f)) |
                  ((unsigned)f2bf(fmaxf(acc[8 * g + 7], 0.f)) << 16);
    o4[g] = uint4{u0, u1, u2, u3};
  }
}

// ---------------- conv3x3 via bf16 MFMA implicit GEMM ----------------
// in: [8][PPLANE][64] bf16 NHWC padded (borders zero)
// wb: [9][COUT][64] bf16 ([tap][co][ci])
// out: [8][COUT][HW] fp32 NCHW, bias+relu applied
template <int COUT>
__global__ __launch_bounds__(256) void conv3x3_mfma_k(
    const ushort* __restrict__ in, const ushort* __restrict__ wb,
    const float* __restrict__ bias, float* __restrict__ out) {
  constexpr int NF = COUT / 16;
  __shared__ ushort As[272 * 72];       // [m_window][k=ci], stride 72
  __shared__ ushort Bs[3 * COUT * 64];  // [dx][n][k], xor-swizzled k-blocks
  const int tile = blockIdx.x, img = blockIdx.y;
  const int pp0 = PW + tile * 256; // first output padded-pixel of tile
  const int tid = threadIdx.x, wave = tid >> 6, lane = tid & 63;
  const int lm = lane & 15, lq = lane >> 4;
  const ushort* inb = in + (size_t)img * PPLANE * 64;

  f32x4 acc[4][NF];
#pragma unroll
  for (int mf = 0; mf < 4; mf++)
#pragma unroll
    for (int nf = 0; nf < NF; nf++) acc[mf][nf] = f32x4{0.f, 0.f, 0.f, 0.f};

  for (int dy = 0; dy < 3; dy++) {
    __syncthreads();
    // stage A window: 272 m x 64 ci, contiguous NHWC rows
    long abase = ((long)pp0 + (long)(dy - 1) * PW - 8) * 64;
    for (int i = tid; i < 272 * 8; i += 256) {
      int m = i >> 3, kseg = i & 7;
      uint4 v = *(const uint4*)(inb + abase + (long)m * 64 + kseg * 8);
      *(uint4*)&As[m * 72 + kseg * 8] = v;
    }
    // stage B: taps (dy,0..2), [n][k] with k-block xor swizzle
    for (int i = tid; i < 3 * COUT * 8; i += 256) {
      int dx = i / (COUT * 8);
      int r = i % (COUT * 8);
      int co = r >> 3, kseg = r & 7;
      uint4 v = *(const uint4*)(wb + (((size_t)(dy * 3 + dx) * COUT + co) << 6) + kseg * 8);
      *(uint4*)&Bs[(dx * COUT + co) * 64 + ((kseg ^ (co & 7)) * 8)] = v;
    }
    __syncthreads();
#pragma unroll
    for (int dx = 0; dx < 3; dx++) {
#pragma unroll
      for (int kc = 0; kc < 2; kc++) {
        bf16x8 bfr[NF];
#pragma unroll
        for (int nf = 0; nf < NF; nf++) {
          int n = nf * 16 + lm;
          int kb = kc * 4 + lq;
          bfr[nf] = *(const bf16x8*)&Bs[(dx * COUT + n) * 64 + ((kb ^ (n & 7)) * 8)];
        }
#pragma unroll
        for (int mf = 0; mf < 4; mf++) {
          int mo = (wave * 4 + mf) * 16 + lm;
          bf16x8 afr = *(const bf16x8*)&As[(mo + dx + 7) * 72 + kc * 32 + lq * 8];
#pragma unroll
          for (int nf = 0; nf < NF; nf++)
            acc[mf][nf] = __builtin_amdgcn_mfma_f32_16x16x32_bf16(afr, bfr[nf],
                                                                  acc[mf][nf], 0, 0, 0);
        }
      }
    }
  }
  // epilogue: bias + relu, store valid pixels to fp32 NCHW
  float bv[NF];
#pragma unroll
  for (int nf = 0; nf < NF; nf++) bv[nf] = bias[nf * 16 + lm];
#pragma unroll
  for (int mf = 0; mf < 4; mf++) {
#pragma unroll
    for (int nf = 0; nf < NF; nf++) {
      int co = nf * 16 + lm;
      float* ob = out + ((size_t)img * COUT + co) * HW;
#pragma unroll
      for (int r = 0; r < 4; r++) {
        int mo = pp0 + (wave * 4 + mf) * 16 + lq * 4 + r;
        int py = mo / PW, px = mo % PW;
        if (py >= 1 && py <= H && px >= 1 && px <= W) {
          float v = fmaxf(acc[mf][nf][r] + bv[nf], 0.f);
          ob[(py - 1) * W + (px - 1)] = v;
        }
      }
    }
  }
}

// ---------------- 81-offset correlation + fused softmax ----------------
__global__ __launch_bounds__(256) void corr_softmax_k(
    const float* __restrict__ e, float* __restrict__ wgt) {
  __shared__ float tile[16 * TLD * TROW];
  int tileId = blockIdx.x;
  int tx0 = (tileId % NTILE) * TS, ty0 = (tileId / NTILE) * TS;
  int bb = blockIdx.y;
  int lx = threadIdx.x % TS, ly = threadIdx.x / TS;
  int x = tx0 + lx, y = ty0 + ly;
  bool active = (x < W && y < H);
  const float* es_base = e + (size_t)bb * 64 * HW + (active ? y * W + x : 0);
  const float* ec_base = e + (size_t)(bb + B) * 64 * HW;
  float acc[NK];
#pragma unroll
  for (int k = 0; k < NK; k++) acc[k] = 0.f;
  for (int cc = 0; cc < 4; cc++) {
    __syncthreads();
    for (int i = threadIdx.x; i < TLD * TLD; i += 256) {
      int row = i / TLD, col = i % TLD;
      int gy = ty0 + row - HALO, gx = tx0 + col - HALO;
      bool v = (gy >= 0 && gy < H && gx >= 0 && gx < W);
      const float* p = ec_base + (size_t)(cc * 16) * HW + (v ? gy * W + gx : 0);
#pragma unroll
      for (int c = 0; c < 16; c++)
        tile[c * (TLD * TROW) + row * TROW + col] = v ? p[(size_t)c * HW] : 0.f;
    }
    __syncthreads();
    if (active) {
#pragma unroll
      for (int c = 0; c < 16; c++) {
        float es = es_base[(size_t)(cc * 16 + c) * HW];
        const float* tp = &tile[c * (TLD * TROW) + (ly + HALO) * TROW + (lx + HALO)];
#pragma unroll
        for (int k = 0; k < NK; k++) {
          int di = k / 9 - 4, dj = k % 9 - 4;
          acc[k] += es * tp[di * TROW + dj];
        }
      }
    }
  }
  if (!active) return;
  float m = acc[0];
#pragma unroll
  for (int k = 1; k < NK; k++) m = fmaxf(m, acc[k]);
  float ssum = 0.f;
#pragma unroll
  for (int k = 0; k < NK; k++) {
    acc[k] = expf(acc[k] - m);
    ssum += acc[k];
  }
  float inv = 1.f / ssum;
  int pix = y * W + x;
  float* wp = wgt + (size_t)bb * NK * HW + pix;
#pragma unroll
  for (int k = 0; k < NK; k++) wp[(size_t)k * HW] = acc[k] * inv;
}

// ---------------- weighted neighborhood aggregation (align) ----------------
__global__ __launch_bounds__(256) void align_k(
    const float* __restrict__ wgt, const float* __restrict__ fs,
    float* __restrict__ out) {
  __shared__ float tile[16 * TLD * TROW];
  int tileId = blockIdx.x;
  int tx0 = (tileId % NTILE) * TS, ty0 = (tileId / NTILE) * TS;
  int bb = blockIdx.y;
  int lx = threadIdx.x % TS, ly = threadIdx.x / TS;
  int x = tx0 + lx, y = ty0 + ly;
  bool active = (x < W && y < H);
  int pix = active ? y * W + x : 0;
  const float* fsb = fs + (size_t)bb * 128 * HW;
  float wreg[NK];
  const float* wp = wgt + (size_t)bb * NK * HW + pix;
#pragma unroll
  for (int k = 0; k < NK; k++) wreg[k] = wp[(size_t)k * HW];
  float* ob = out + (size_t)bb * 128 * HW + pix;
  for (int cc = 0; cc < 8; cc++) {
    __syncthreads();
    for (int i = threadIdx.x; i < TLD * TLD; i += 256) {
      int row = i / TLD, col = i % TLD;
      int gy = ty0 + row - HALO, gx = tx0 + col - HALO;
      bool v = (gy >= 0 && gy < H && gx >= 0 && gx < W);
      const float* p = fsb + (size_t)(cc * 16) * HW + (v ? gy * W + gx : 0);
#pragma unroll
      for (int c = 0; c < 16; c++)
        tile[c * (TLD * TROW) + row * TROW + col] = v ? p[(size_t)c * HW] : 0.f;
    }
    __syncthreads();
    if (active) {
      float acc2[16];
#pragma unroll
      for (int c = 0; c < 16; c++) acc2[c] = 0.f;
#pragma unroll
      for (int c = 0; c < 16; c++) {
        const float* tp = &tile[c * (TLD * TROW) + (ly + HALO) * TROW + (lx + HALO)];
#pragma unroll
        for (int k = 0; k < NK; k++) {
          int di = k / 9 - 4, dj = k % 9 - 4;
          acc2[c] += wreg[k] * tp[di * TROW + dj];
        }
      }
#pragma unroll
      for (int c = 0; c < 16; c++) ob[(size_t)(cc * 16 + c) * HW] = acc2[c];
    }
  }
}

// ---------------- ag3 conv1x1 (32->1) + relu + 2-way softmax + blend ----------------
__global__ __launch_bounds__(256) void final_k(
    const float* __restrict__ a2, const float* __restrict__ w3,
    const float* __restrict__ b3, const float* __restrict__ alignb,
    const float* __restrict__ fcur, float* __restrict__ out) {
  int p = blockIdx.x * 256 + threadIdx.x;
  int bb = p / HW, pix = p % HW;
  const float* aS = a2 + (size_t)bb * 32 * HW + pix;
  const float* aC = a2 + (size_t)(bb + B) * 32 * HW + pix;
  float s0 = b3[0], s1 = b3[0];
#pragma unroll
  for (int c = 0; c < 32; c++) {
    float wv = w3[c];
    s0 += wv * aS[(size_t)c * HW];
    s1 += wv * aC[(size_t)c * HW];
  }
  s0 = fmaxf(s0, 0.f);
  s1 = fmaxf(s1, 0.f);
  float m = fmaxf(s0, s1);
  float e0 = expf(s0 - m), e1 = expf(s1 - m);
  float inv = 1.f / (e0 + e1);
  float p0 = e0 * inv, p1 = e1 * inv;
  const float* al = alignb + (size_t)bb * 128 * HW + pix;
  const float* fc = fcur + (size_t)bb * 128 * HW + pix;
  float* o = out + (size_t)bb * 128 * HW + pix;
#pragma unroll 4
  for (int c = 0; c < 128; c++)
    o[(size_t)c * HW] = p0 * al[(size_t)c * HW] + p1 * fc[(size_t)c * HW];
}

extern "C" void kernel_launch(void* const* d_in, const int* in_sizes, int n_in,
                              void* d_out, int out_size, void* d_ws, size_t ws_size,
                              hipStream_t stream) {
  const float* fsel = (const float*)d_in[0];
  const float* fcur = (const float*)d_in[1];
  const float* ec1_w = (const float*)d_in[2];
  const float* ec1_b = (const float*)d_in[3];
  const float* ec2_w = (const float*)d_in[4];
  const float* ec2_b = (const float*)d_in[5];
  const float* ag1_w = (const float*)d_in[6];
  const float* ag1_b = (const float*)d_in[7];
  const float* ag2_w = (const float*)d_in[8];
  const float* ag2_b = (const float*)d_in[9];
  const float* ag3_w = (const float*)d_in[10];
  const float* ag3_b = (const float*)d_in[11];

  char* ws = (char*)d_ws;
  size_t off = 4096; // guard for negative-offset halo reads
  ushort* padbuf = (ushort*)(ws + off);              // e1pad then a1pad
  off += (size_t)8 * PPLANE * 64 * 2;                // 43.0 MB
  float* e = (float*)(ws + off);                     // e (8,64,HW) then alignb (4,128,HW)
  off += (size_t)8 * 64 * HW * 4;                    // 81.9 MB
  float* wgt = (float*)(ws + off);                   // wgt (4,81,HW) then a2 (8,32,HW)
  off += (size_t)4 * NK * HW * 4;                    // 51.8 MB
  ushort* wb1 = (ushort*)(ws + off);
  off += 9 * 64 * 64 * 2;
  ushort* wb2 = (ushort*)(ws + off);
  off += 9 * 32 * 64 * 2;
  float* alignb = e;   // reuse e region after corr
  float* a2 = wgt;     // reuse wgt region after align
  float* outp = (float*)d_out;

  dim3 blk(256);
  const int MTILES = (200 * PW + 255) / 256; // 163

  // weight transforms (bf16 [tap][co][ci])
  wxform_k<<<(9 * 64 * 64 + 255) / 256, blk, 0, stream>>>(ec2_w, wb1, 64);
  wxform_k<<<(9 * 32 * 64 + 255) / 256, blk, 0, stream>>>(ag2_w, wb2, 32);
  // zero padded buffer (borders must be 0; interior overwritten)
  int nz = (int)((size_t)8 * PPLANE * 64 * 2 / 16);
  zero_k<<<(nz + 255) / 256, blk, 0, stream>>>((uint4*)padbuf, nz);
  // e1pad = relu(conv1x1(cat, ec1))  bf16 NHWC padded
  conv1x1_nhwc_k<128><<<1250, blk, 0, stream>>>(fsel, fcur, ec1_w, ec1_b, padbuf);
  // e = relu(conv3x3(e1pad, ec2))    fp32 NCHW
  conv3x3_mfma_k<64><<<dim3(MTILES, 8), blk, 0, stream>>>(padbuf, wb1, ec2_b, e);
  // wgt = softmax(corr)
  corr_softmax_k<<<dim3(NTILE * NTILE, B), blk, 0, stream>>>(e, wgt);
  // alignb = weighted aggregation (overwrites e region — e is dead)
  align_k<<<dim3(NTILE * NTILE, B), blk, 0, stream>>>(wgt, fsel, alignb);
  // a1pad = relu(conv1x1(cat(align,fcur), ag1))  (reuse padbuf; borders still 0)
  conv1x1_nhwc_k<128><<<1250, blk, 0, stream>>>(alignb, fcur, ag1_w, ag1_b, padbuf);
  // a2 = relu(conv3x3(a1pad, ag2))   fp32 NCHW (overwrites wgt region — dead)
  conv3x3_mfma_k<32><<<dim3(MTILES, 8), blk, 0, stream>>>(padbuf, wb2, ag2_b, a2);
  // out
  final_k<<<625, blk, 0, stream>>>(a2, ag3_w, ag3_b, alignb, fcur, outp);
}

// Round 4
// 904.451 us; speedup vs baseline: 2.7596x; 1.8151x over previous
//
#include <hip/hip_runtime.h>

namespace {
constexpr int H = 200, W = 200, HW = H * W;
constexpr int Bz = 4;
constexpr int PW = 208, PH = 202, PPLANE = PW * PH; // conv1x1 pad geometry (halo 1)
constexpr int EPW = 208, EPH = 208, EPL = EPW * EPH; // e-pad geometry (halo 4)
constexpr int WST = 88; // wgt row stride in u16 (81 used, padded to 8-mult)
}

typedef __attribute__((ext_vector_type(8))) short bf16x8;
typedef __attribute__((ext_vector_type(4))) float f32x4;

__device__ inline ushort f2bf(float f) {
  unsigned u = __float_as_uint(f);
  u += 0x7fffu + ((u >> 16) & 1u);
  return (ushort)(u >> 16);
}

// ---------------- zero fill ----------------
__global__ __launch_bounds__(256) void zero_k(uint4* __restrict__ p, int n) {
  int i = blockIdx.x * 256 + threadIdx.x;
  if (i < n) p[i] = uint4{0u, 0u, 0u, 0u};
}

// ---------------- weight transform: OIHW fp32 -> [tap][co][ci] bf16 ----------------
__global__ __launch_bounds__(256) void wxform_k(const float* __restrict__ w,
                                                ushort* __restrict__ wb, int cout) {
  int i = blockIdx.x * 256 + threadIdx.x;
  int tot = cout * 64 * 9;
  if (i >= tot) return;
  int co = i / (64 * 9);
  int r = i % (64 * 9);
  int ci = r / 9, tap = r % 9;
  wb[(tap * cout + co) * 64 + ci] = f2bf(w[i]);
}

// ---------------- conv1x1 + bias + relu -> bf16 NHWC padded (halo 1) ----------------
template <int CIN>
__global__ __launch_bounds__(256) void conv1x1_nhwc_k(
    const float* __restrict__ srcA, const float* __restrict__ srcB,
    const float* __restrict__ w, const float* __restrict__ bias,
    ushort* __restrict__ out) {
  __shared__ float wt[CIN * 64];
  for (int i = threadIdx.x; i < CIN * 64; i += 256) {
    int ci = i >> 6, co = i & 63;
    wt[i] = w[co * CIN + ci];
  }
  __syncthreads();
  int p = blockIdx.x * 256 + threadIdx.x;
  int bb = p / HW, pix = p % HW;
  const float* src =
      (bb < Bz ? srcA + (size_t)bb * CIN * HW : srcB + (size_t)(bb - Bz) * CIN * HW) + pix;
  float acc[64];
#pragma unroll
  for (int co = 0; co < 64; co++) acc[co] = bias[co];
  for (int ci = 0; ci < CIN; ci++) {
    float x = src[(size_t)ci * HW];
    const float4* w4 = (const float4*)&wt[ci * 64];
#pragma unroll
    for (int q = 0; q < 16; q++) {
      float4 wv = w4[q];
      acc[4 * q + 0] += x * wv.x;
      acc[4 * q + 1] += x * wv.y;
      acc[4 * q + 2] += x * wv.z;
      acc[4 * q + 3] += x * wv.w;
    }
  }
  int y = pix / W, x = pix % W;
  ushort* o = out + ((size_t)bb * PPLANE + (size_t)(y + 1) * PW + (x + 1)) * 64;
  uint4* o4 = (uint4*)o;
#pragma unroll
  for (int g = 0; g < 8; g++) {
    unsigned u0 = (unsigned)f2bf(fmaxf(acc[8 * g + 0], 0.f)) |
                  ((unsigned)f2bf(fmaxf(acc[8 * g + 1], 0.f)) << 16);
    unsigned u1 = (unsigned)f2bf(fmaxf(acc[8 * g + 2], 0.f)) |
                  ((unsigned)f2bf(fmaxf(acc[8 * g + 3], 0.f)) << 16);
    unsigned u2 = (unsigned)f2bf(fmaxf(acc[8 * g + 4], 0.f)) |
                  ((unsigned)f2bf(fmaxf(acc[8 * g + 5], 0.f)) << 16);
    unsigned u3 = (unsigned)f2bf(fmaxf(acc[8 * g + 6], 0.f)) |
                  ((unsigned)f2bf(fmaxf(acc[8 * g + 7], 0.f)) << 16);
    o4[g] = uint4{u0, u1, u2, u3};
  }
}

// ---------------- conv3x3 via bf16 MFMA implicit GEMM ----------------
template <int COUT, bool NHWC>
__global__ __launch_bounds__(256) void conv3x3_mfma_k(
    const ushort* __restrict__ in, const ushort* __restrict__ wb,
    const float* __restrict__ bias, float* __restrict__ outf,
    ushort* __restrict__ outh) {
  constexpr int NF = COUT / 16;
  __shared__ ushort As[272 * 72];
  __shared__ ushort Bs[3 * COUT * 64];
  const int tile = blockIdx.x, img = blockIdx.y;
  const int pp0 = PW + tile * 256;
  const int tid = threadIdx.x, wave = tid >> 6, lane = tid & 63;
  const int lm = lane & 15, lq = lane >> 4;
  const ushort* inb = in + (size_t)img * PPLANE * 64;

  f32x4 acc[4][NF];
#pragma unroll
  for (int mf = 0; mf < 4; mf++)
#pragma unroll
    for (int nf = 0; nf < NF; nf++) acc[mf][nf] = f32x4{0.f, 0.f, 0.f, 0.f};

  for (int dy = 0; dy < 3; dy++) {
    __syncthreads();
    long abase = ((long)pp0 + (long)(dy - 1) * PW - 8) * 64;
    for (int i = tid; i < 272 * 8; i += 256) {
      int m = i >> 3, kseg = i & 7;
      uint4 v = *(const uint4*)(inb + abase + (long)m * 64 + kseg * 8);
      *(uint4*)&As[m * 72 + kseg * 8] = v;
    }
    for (int i = tid; i < 3 * COUT * 8; i += 256) {
      int dx = i / (COUT * 8);
      int r = i % (COUT * 8);
      int co = r >> 3, kseg = r & 7;
      uint4 v = *(const uint4*)(wb + (((size_t)(dy * 3 + dx) * COUT + co) << 6) + kseg * 8);
      *(uint4*)&Bs[(dx * COUT + co) * 64 + ((kseg ^ (co & 7)) * 8)] = v;
    }
    __syncthreads();
#pragma unroll
    for (int dx = 0; dx < 3; dx++) {
#pragma unroll
      for (int kc = 0; kc < 2; kc++) {
        bf16x8 bfr[NF];
#pragma unroll
        for (int nf = 0; nf < NF; nf++) {
          int n = nf * 16 + lm;
          int kb = kc * 4 + lq;
          bfr[nf] = *(const bf16x8*)&Bs[(dx * COUT + n) * 64 + ((kb ^ (n & 7)) * 8)];
        }
#pragma unroll
        for (int mf = 0; mf < 4; mf++) {
          int mo = (wave * 4 + mf) * 16 + lm;
          bf16x8 afr = *(const bf16x8*)&As[(mo + dx + 7) * 72 + kc * 32 + lq * 8];
#pragma unroll
          for (int nf = 0; nf < NF; nf++)
            acc[mf][nf] = __builtin_amdgcn_mfma_f32_16x16x32_bf16(afr, bfr[nf],
                                                                  acc[mf][nf], 0, 0, 0);
        }
      }
    }
  }
  float bv[NF];
#pragma unroll
  for (int nf = 0; nf < NF; nf++) bv[nf] = bias[nf * 16 + lm];
#pragma unroll
  for (int mf = 0; mf < 4; mf++) {
#pragma unroll
    for (int nf = 0; nf < NF; nf++) {
      int co = nf * 16 + lm;
#pragma unroll
      for (int r = 0; r < 4; r++) {
        int mo = pp0 + (wave * 4 + mf) * 16 + lq * 4 + r;
        int py = mo / PW, px = mo % PW;
        if (py >= 1 && py <= H && px >= 1 && px <= W) {
          float v = fmaxf(acc[mf][nf][r] + bv[nf], 0.f);
          if (NHWC) {
            ushort* eo = outh + (size_t)img * EPL * 64;
            eo[(((size_t)(py + 3)) * EPW + (px + 3)) * 64 + co] = f2bf(v);
          } else {
            outf[((size_t)img * COUT + co) * HW + (py - 1) * W + (px - 1)] = v;
          }
        }
      }
    }
  }
}

// ---------------- correlation via banded MFMA + fused softmax ----------------
__global__ __launch_bounds__(128) void corr_mfma_k(
    const ushort* __restrict__ e, ushort* __restrict__ wgt) {
  __shared__ float S[2 * 16 * 91];
  const int wave = threadIdx.x >> 6, lane = threadIdx.x & 63;
  const int x0 = blockIdx.x * 16;
  const int y = blockIdx.y * 2 + wave;
  const int b = blockIdx.z;
  const int nl = lane & 15, kq = lane >> 4;
  const ushort* es = e + (size_t)b * EPL * 64;
  const ushort* ec = e + (size_t)(b + 4) * EPL * 64;
  size_t abase = ((size_t)(y + 4) * EPW + (size_t)(4 + x0 + nl)) * 64 + kq * 8;
  bf16x8 afr0 = *(const bf16x8*)(es + abase);
  bf16x8 afr1 = *(const bf16x8*)(es + abase + 32);
  float* Sw = &S[wave * 16 * 91];
  for (int di = 0; di < 9; di++) {
    const ushort* erow = ec + ((size_t)(y + di) * EPW + x0) * 64;
#pragma unroll
    for (int nh = 0; nh < 2; nh++) {
      f32x4 g = f32x4{0.f, 0.f, 0.f, 0.f};
      const ushort* bp = erow + (size_t)(nh * 16 + nl) * 64 + kq * 8;
      bf16x8 b0 = *(const bf16x8*)(bp);
      bf16x8 b1 = *(const bf16x8*)(bp + 32);
      g = __builtin_amdgcn_mfma_f32_16x16x32_bf16(afr0, b0, g, 0, 0, 0);
      g = __builtin_amdgcn_mfma_f32_16x16x32_bf16(afr1, b1, g, 0, 0, 0);
      int q = nh * 16 + nl;
#pragma unroll
      for (int r = 0; r < 4; r++) {
        int m = kq * 4 + r;
        int s = q - m;
        if (s >= 0 && s <= 8) Sw[m * 91 + di * 9 + s] = g[r];
      }
    }
  }
  int px = lane >> 2, lg = lane & 3;
  float* Sp = &Sw[px * 91];
  float mx = -1e30f;
  for (int k = lg; k < 81; k += 4) mx = fmaxf(mx, Sp[k]);
  mx = fmaxf(mx, __shfl_xor(mx, 1));
  mx = fmaxf(mx, __shfl_xor(mx, 2));
  float sum = 0.f;
  for (int k = lg; k < 81; k += 4) {
    float t = expf(Sp[k] - mx);
    Sp[k] = t;
    sum += t;
  }
  sum += __shfl_xor(sum, 1);
  sum += __shfl_xor(sum, 2);
  float rinv = 1.f / sum;
  if (x0 + px < W) {
    ushort* wp = wgt + ((size_t)b * 40000 + (size_t)y * W + x0 + px) * WST;
    for (int k = lg; k < 81; k += 4) wp[k] = f2bf(Sp[k] * rinv);
  }
}

// ---------------- align via banded MFMA ----------------
__global__ __launch_bounds__(256) void align_mfma_k(
    const ushort* __restrict__ wgt, const float* __restrict__ fs,
    float* __restrict__ out) {
  __shared__ ushort F[32 * 392];    // [ch][row*24+pos], c-stride 392
  __shared__ ushort WT[128 * WST];  // [tile_px][WST]
  const int x0 = blockIdx.x * 16, y0 = blockIdx.y * 8;
  const int b = blockIdx.z & 3, cs = blockIdx.z >> 2;
  const int c0 = cs * 32;
  const int tid = threadIdx.x;
  {
    const ushort* wb = wgt + (size_t)b * 40000 * WST;
    for (int i = tid; i < 1408; i += 256) {
      int row = i / 176, rem = i % 176;
      size_t src = ((size_t)(y0 + row) * W + x0) * WST + (size_t)rem * 8;
      *(uint4*)&WT[(size_t)row * 16 * WST + rem * 8] = *(const uint4*)(wb + src);
    }
  }
  // stage features over FULL c-stride extent (392): entries 384..391 zeroed.
  // (R3 bug: tail was unstaged LDS -> 0 x NaN in MFMA -> NaN cascade.)
  const float* fb = fs + ((size_t)b * 128 + c0) * HW;
  for (int i = tid; i < 32 * 392; i += 256) {
    int c = i / 392, rem = i % 392;
    int row = rem / 24, pos = rem % 24;
    int gy = y0 + row - 4, gx = x0 + pos - 4;
    float v = (rem < 384 && gy >= 0 && gy < H && gx >= 0 && gx < W)
                  ? fb[(size_t)c * HW + gy * W + gx] : 0.f;
    F[c * 392 + rem] = f2bf(v);
  }
  __syncthreads();
  const int wave = tid >> 6, lane = tid & 63;
  const int nl = lane & 15, kq = lane >> 4;
  f32x4 acc[2][2];
#pragma unroll
  for (int s = 0; s < 2; s++)
#pragma unroll
    for (int cg = 0; cg < 2; cg++) acc[s][cg] = f32x4{0.f, 0.f, 0.f, 0.f};

#pragma unroll
  for (int s = 0; s < 2; s++) {
    int r = wave * 2 + s;
    const ushort* wrow = &WT[(size_t)(r * 16 + nl) * WST];
    for (int di = 0; di < 9; di++) {
      union { bf16x8 v; ushort u[8]; } A;
#pragma unroll
      for (int j = 0; j < 8; j++) {
        int t = kq * 8 + j - nl;
        int tc = t < 0 ? 0 : (t > 8 ? 8 : t);
        ushort wv = wrow[di * 9 + tc];
        A.u[j] = (t == tc) ? wv : (ushort)0;
      }
#pragma unroll
      for (int cg = 0; cg < 2; cg++) {
        bf16x8 bfr = *(const bf16x8*)&F[(size_t)(cg * 16 + nl) * 392 +
                                        (r + di) * 24 + kq * 8];
        acc[s][cg] =
            __builtin_amdgcn_mfma_f32_16x16x32_bf16(A.v, bfr, acc[s][cg], 0, 0, 0);
      }
    }
  }
  int mg = lane >> 4;
  int x4 = x0 + mg * 4;
  if (x4 + 3 < W) {
#pragma unroll
    for (int s = 0; s < 2; s++) {
      int yy = y0 + wave * 2 + s;
#pragma unroll
      for (int cg = 0; cg < 2; cg++) {
        int cgl = c0 + cg * 16 + nl;
        float4 st = float4{acc[s][cg][0], acc[s][cg][1], acc[s][cg][2], acc[s][cg][3]};
        *(float4*)&out[((size_t)b * 128 + cgl) * HW + (size_t)yy * W + x4] = st;
      }
    }
  }
}

// ---------------- ag3 conv1x1 (32->1) + relu + 2-way softmax + blend ----------------
__global__ __launch_bounds__(256) void final_k(
    const float* __restrict__ a2, const float* __restrict__ w3,
    const float* __restrict__ b3, const float* __restrict__ alignb,
    const float* __restrict__ fcur, float* __restrict__ out) {
  int p = blockIdx.x * 256 + threadIdx.x;
  int bb = p / HW, pix = p % HW;
  const float* aS = a2 + (size_t)bb * 32 * HW + pix;
  const float* aC = a2 + (size_t)(bb + Bz) * 32 * HW + pix;
  float s0 = b3[0], s1 = b3[0];
#pragma unroll
  for (int c = 0; c < 32; c++) {
    float wv = w3[c];
    s0 += wv * aS[(size_t)c * HW];
    s1 += wv * aC[(size_t)c * HW];
  }
  s0 = fmaxf(s0, 0.f);
  s1 = fmaxf(s1, 0.f);
  float m = fmaxf(s0, s1);
  float e0 = expf(s0 - m), e1 = expf(s1 - m);
  float inv = 1.f / (e0 + e1);
  float p0 = e0 * inv, p1 = e1 * inv;
  const float* al = alignb + (size_t)bb * 128 * HW + pix;
  const float* fc = fcur + (size_t)bb * 128 * HW + pix;
  float* o = out + (size_t)bb * 128 * HW + pix;
#pragma unroll 4
  for (int c = 0; c < 128; c++)
    o[(size_t)c * HW] = p0 * al[(size_t)c * HW] + p1 * fc[(size_t)c * HW];
}

extern "C" void kernel_launch(void* const* d_in, const int* in_sizes, int n_in,
                              void* d_out, int out_size, void* d_ws, size_t ws_size,
                              hipStream_t stream) {
  const float* fsel = (const float*)d_in[0];
  const float* fcur = (const float*)d_in[1];
  const float* ec1_w = (const float*)d_in[2];
  const float* ec1_b = (const float*)d_in[3];
  const float* ec2_w = (const float*)d_in[4];
  const float* ec2_b = (const float*)d_in[5];
  const float* ag1_w = (const float*)d_in[6];
  const float* ag1_b = (const float*)d_in[7];
  const float* ag2_w = (const float*)d_in[8];
  const float* ag2_b = (const float*)d_in[9];
  const float* ag3_w = (const float*)d_in[10];
  const float* ag3_b = (const float*)d_in[11];

  char* ws = (char*)d_ws;
  size_t off = 4096;
  ushort* padbuf = (ushort*)(ws + off);
  size_t padbuf_bytes = (size_t)8 * PPLANE * 64 * 2;
  off += padbuf_bytes;
  ushort* epad = (ushort*)(ws + off);
  size_t epad_bytes = (size_t)8 * EPL * 64 * 2;
  off += epad_bytes + 4096;
  ushort* wgtb = (ushort*)(ws + off);
  off += (size_t)4 * 40000 * WST * 2 + 4096;
  float* alignb = (float*)(ws + off);
  off += (size_t)4 * 128 * HW * 4;
  ushort* wb1 = (ushort*)(ws + off);
  off += 9 * 64 * 64 * 2;
  ushort* wb2 = (ushort*)(ws + off);
  off += 9 * 32 * 64 * 2;
  float* a2 = (float*)epad;
  float* outp = (float*)d_out;

  dim3 blk(256);
  const int MTILES = (200 * PW + 255) / 256; // 163

  wxform_k<<<(9 * 64 * 64 + 255) / 256, blk, 0, stream>>>(ec2_w, wb1, 64);
  wxform_k<<<(9 * 32 * 64 + 255) / 256, blk, 0, stream>>>(ag2_w, wb2, 32);
  {
    int nz = (int)((padbuf_bytes + epad_bytes) / 16);
    zero_k<<<(nz + 255) / 256, blk, 0, stream>>>((uint4*)padbuf, nz);
  }
  conv1x1_nhwc_k<128><<<1250, blk, 0, stream>>>(fsel, fcur, ec1_w, ec1_b, padbuf);
  conv3x3_mfma_k<64, true><<<dim3(MTILES, 8), blk, 0, stream>>>(
      padbuf, wb1, ec2_b, nullptr, epad);
  corr_mfma_k<<<dim3(13, 100, 4), dim3(128), 0, stream>>>(epad, wgtb);
  align_mfma_k<<<dim3(13, 25, 16), blk, 0, stream>>>(wgtb, fsel, alignb);
  conv1x1_nhwc_k<128><<<1250, blk, 0, stream>>>(alignb, fcur, ag1_w, ag1_b, padbuf);
  conv3x3_mfma_k<32, false><<<dim3(MTILES, 8), blk, 0, stream>>>(
      padbuf, wb2, ag2_b, a2, nullptr);
  final_k<<<625, blk, 0, stream>>>(a2, ag3_w, ag3_b, alignb, fcur, outp);
}